// Round 9
// baseline (489.451 us; speedup 1.0000x reference)
//
#include <hip/hip_runtime.h>

typedef __attribute__((ext_vector_type(8))) short short8;
typedef __attribute__((ext_vector_type(8))) __bf16 bf16x8;
typedef __attribute__((ext_vector_type(4))) float f32x4;

__device__ __forceinline__ short f2bf(float f) {
    union { float f; unsigned u; } x; x.f = f;
    unsigned r = (x.u + 0x7FFFu + ((x.u >> 16) & 1u)) >> 16;
    return (short)r;
}

__device__ __forceinline__ f32x4 mfma16(bf16x8 a, bf16x8 b, f32x4 c) {
    return __builtin_amdgcn_mfma_f32_16x16x32_bf16(a, b, c, 0, 0, 0);
}

// LDS 16B-slot swizzle: injects slot bits 4-6 into bank bits. (R7: 0 conflicts)
__device__ __forceinline__ int swz(int slot) { return slot ^ ((slot >> 4) & 7); }

// ---------------------------------------------------------------------------
// Weight repack: fp32 row-major -> bf16 MFMA-B fragment order.
// Chunk c = nf*nK + t holds (k=32 x n=16): lane l owns 8 bf16 at
// k = t*32 + (l>>4)*8 + j, n = nf*16 + (l&15).
// Big (nK=98) variants append rows: [src0(2052) | 0 | srcq(1024) | bias | 0].
// perm=1 (nK=32): source row pr = (kk&~127)|((kk&7)<<4)|((kk>>3)&15)  (pi^-1
// of the fused epilogue's Y k'-pack for the 128-col wave tile; audited r8).
// ---------------------------------------------------------------------------
struct WConvP {
    const float* src0[8];
    const float* srcq[8];
    const float* bias[8];
    short*       dst[8];
    int          n0[8];
    int          nK[8];
    int          perm[8];
};

__global__ __launch_bounds__(256) void k_wconv(WConvP P) {
    int y = blockIdx.y;
    int nK = P.nK[y];
    int nchunks = nK << 6;
    int c = blockIdx.x * 4 + (threadIdx.x >> 6);
    if (c >= nchunks) return;
    int l = threadIdx.x & 63;
    int t = c % nK, nf = c / nK;
    int k0 = (t << 5) + ((l >> 4) << 3);
    int n  = (nf << 4) + (l & 15);
    const float* src0 = P.src0[y];
    const float* srcq = P.srcq[y];
    const float* bias = P.bias[y];
    int n0 = P.n0[y], pm = P.perm[y];
    short8 v;
#pragma unroll
    for (int j = 0; j < 8; ++j) {
        int kk = k0 + j;
        float f = 0.f;
        if (pm) {
            int pr = (kk & ~127) | ((kk & 7) << 4) | ((kk >> 3) & 15);
            f = src0[(size_t)pr * 1024 + n];
        } else if (kk < n0) {
            f = src0[(size_t)kk * 1024 + n];
        } else if (srcq && kk >= 2080 && kk < 3104) {
            f = srcq[(size_t)(kk - 2080) * 1024 + n];
        } else if (bias && kk == 3104) {
            f = bias[n];
        }
        v[j] = f2bf(f);
    }
    ((short8*)P.dst[y])[(size_t)c * 64 + l] = v;
}

// ---------------------------------------------------------------------------
// Build bf16 padded X rows.
// bfcq row (b,i), K=3136: [box_feats|box_coords|0x28|q[b]|1.0|0x31]
// pc   row (b,j), K=2080: [pooled|pool_coords|0x28]
// ---------------------------------------------------------------------------
__global__ __launch_bounds__(256) void k_build(const float* box_feats, const float* box_coords,
                                               const float* pooled, const float* pool_coords,
                                               const float* q_feats, short* bfcq, short* pc) {
    int id = blockIdx.x * 256 + threadIdx.x;
    if (blockIdx.y == 0) {
        if (id >= 512 * 3136) return;
        int row = id / 3136, kp = id - row * 3136;
        int b = row >> 7, i = row & 127;
        float v = 0.f;
        if (kp < 2048)       v = box_feats[((size_t)(b * 128 + i)) * 2048 + kp];
        else if (kp < 2052)  v = box_coords[(b * 128 + i) * 4 + (kp - 2048)];
        else if (kp >= 2080 && kp < 3104) v = q_feats[b * 1024 + (kp - 2080)];
        else if (kp == 3104) v = 1.0f;
        bfcq[id] = f2bf(v);
    } else {
        if (id >= 64 * 2080) return;
        int row = id / 2080, kp = id - row * 2080;
        int b = row >> 4, j = row & 15;
        float v = 0.f;
        if (kp < 2048)      v = pooled[((size_t)(b * 16 + j)) * 2048 + kp];
        else if (kp < 2052) v = pool_coords[j * 4 + (kp - 2048)];
        pc[id] = f2bf(v);
    }
}

// ---------------------------------------------------------------------------
// Stage-1 GEMMs, one kernel, 200 blocks x 256 thr (4 waves).
// Block: 32 rows x 256 cols. z0:A1(K98) z1:B1(K65) z2:A2(K98) z3:P2(K65).
// hq + first-layer bias folded into A-paths via the appended X columns.
// ---------------------------------------------------------------------------
struct S1P {
    const short*  X[4];
    const short8* Wf[4];
    float*        Out[4];
    int           xstr[4];
    int           nK[4];
};

__global__ __launch_bounds__(256) void k_stage1(S1P P) {
    int bid = blockIdx.x;
    int z, idx;
    if (bid < 64)       { z = 0; idx = bid; }
    else if (bid < 128) { z = 1; idx = bid - 64; }
    else if (bid < 192) { z = 2; idx = bid - 128; }
    else                { z = 3; idx = bid - 192; }
    int mt = idx >> 2, panel = idx & 3;
    int m0 = mt << 5;
    const short*  Xg = P.X[z];
    const short8* Wf = P.Wf[z];
    float* Out = P.Out[z];
    int xstr = P.xstr[z], nK = P.nK[z];

    int tid = threadIdx.x, w = tid >> 6, l = tid & 63, lr = l & 15, lh = l >> 4;
    int nfb = (panel << 4) + (w << 2);
    const short8* Wl = Wf + (size_t)nfb * nK * 64 + l;
    f32x4 z4 = {0.f, 0.f, 0.f, 0.f};
    f32x4 acc[2][4];
#pragma unroll
    for (int mf = 0; mf < 2; ++mf)
#pragma unroll
        for (int f = 0; f < 4; ++f) acc[mf][f] = z4;

    for (int t = 0; t < nK; ++t) {
        int k0 = (t << 5) + (lh << 3);
        const short* xb = Xg + (size_t)(m0 + lr) * xstr + k0;
        bf16x8 a0 = __builtin_bit_cast(bf16x8, *(const short8*)xb);
        bf16x8 a1 = __builtin_bit_cast(bf16x8, *(const short8*)(xb + (size_t)16 * xstr));
#pragma unroll
        for (int f = 0; f < 4; ++f) {
            bf16x8 bb = __builtin_bit_cast(bf16x8, Wl[((size_t)f * nK + t) << 6]);
            acc[0][f] = mfma16(a0, bb, acc[0][f]);
            acc[1][f] = mfma16(a1, bb, acc[1][f]);
        }
    }
#pragma unroll
    for (int mf = 0; mf < 2; ++mf)
#pragma unroll
        for (int f = 0; f < 4; ++f)
#pragma unroll
            for (int r = 0; r < 4; ++r) {
                int row = m0 + (mf << 4) + (lh << 2) + r;
                int col = (panel << 8) + (w << 6) + (f << 4) + lr;
                Out[(size_t)row * 1024 + col] = acc[mf][f][r];
            }
}

// ---------------------------------------------------------------------------
// Pipelined 64-row x 128-col-per-wave GEMM over a 64x1024 bf16 LDS tile.
// 1-deep ping-pong W prefetch (wA/wB); setprio around MFMA clusters.
// ---------------------------------------------------------------------------
__device__ __forceinline__ void gemm_pipe(const short8* __restrict__ Wl,
                                          const short8* __restrict__ XLs,
                                          int l, f32x4 (&acc)[4][8]) {
    bf16x8 wA[8], wB[8], av[4];
#pragma unroll
    for (int f = 0; f < 8; ++f)
        wA[f] = __builtin_bit_cast(bf16x8, Wl[f << 11]);
#pragma unroll
    for (int t = 0; t < 32; t += 2) {
#pragma unroll
        for (int f = 0; f < 8; ++f)
            wB[f] = __builtin_bit_cast(bf16x8, Wl[(f << 11) + ((t + 1) << 6)]);
#pragma unroll
        for (int mf = 0; mf < 4; ++mf)
            av[mf] = __builtin_bit_cast(bf16x8, XLs[swz((((mf << 5) + t) << 6) + l)]);
        __builtin_amdgcn_s_setprio(1);
#pragma unroll
        for (int f = 0; f < 8; ++f)
#pragma unroll
            for (int mf = 0; mf < 4; ++mf)
                acc[mf][f] = mfma16(av[mf], wA[f], acc[mf][f]);
        __builtin_amdgcn_s_setprio(0);
        if (t + 2 < 32) {
#pragma unroll
            for (int f = 0; f < 8; ++f)
                wA[f] = __builtin_bit_cast(bf16x8, Wl[(f << 11) + ((t + 2) << 6)]);
        }
#pragma unroll
        for (int mf = 0; mf < 4; ++mf)
            av[mf] = __builtin_bit_cast(bf16x8, XLs[swz((((mf << 5) + (t + 1)) << 6) + l)]);
        __builtin_amdgcn_s_setprio(1);
#pragma unroll
        for (int f = 0; f < 8; ++f)
#pragma unroll
            for (int mf = 0; mf < 4; ++mf)
                acc[mf][f] = mfma16(av[mf], wB[f], acc[mf][f]);
        __builtin_amdgcn_s_setprio(0);
    }
}

// ---------------------------------------------------------------------------
// Fused relation-net tile kernel. M=64 rows, 8 waves (512 thr), 128KB LDS.
// Wave owns 128 output cols (acc[4][8] = 128 AGPR); ~110 VGPR for prefetch.
// g1 (mode 0, blockIdx.x<256) and g2 (mode 1) fused in one dispatch so g2
// tiles backfill g1's tail round.
// phase1: X=relu(A[i]+B[j]) -> GEMM1(W2,relu) -> packed Y (k'=w*128+lr*8+f)
// -> GEMM2(W3 pre-permuted by pi^-1) -> masked row-sum -> atomicAdd gsum.
// ---------------------------------------------------------------------------
struct FuseP {
    const float*  Arow[2];   // hq+bias folded
    const float*  Brow[2];
    const short8* W2[2];
    const short8* W3[2];
    const float*  b2[2];
    const float*  b3[2];
    float*        gsum[2];
    const int*    index;
};

__global__ __launch_bounds__(512, 2) void k_fused(FuseP P) {
    __shared__ short8 XL[8192];                       // 128 KiB
    int b  = blockIdx.y;
    int px = blockIdx.x;
    int mode = (px >= 256) ? 1 : 0;
    int pxl  = mode ? (px - 256) : px;
    int nv = P.index[b];
    int npairs = mode ? (nv << 4) : (nv * nv);
    int p0 = pxl << 6;
    if (p0 >= npairs) return;
    int tid = threadIdx.x, w = tid >> 6, l = tid & 63, lr = l & 15, lh = l >> 4;
    const float* Arow = P.Arow[mode] + (size_t)b * 128 * 1024;
    const float* Brow = P.Brow[mode] + (size_t)b * (mode ? 16 : 128) * 1024;

    // ---- phase 1: X tile. wave w -> (mfp = w>>1, t in (w&1)*16..+15)
    {
        int mfp = w >> 1;
        int p = p0 + (mfp << 4) + lr;
        int i = 0, j = 0;
        if (p < npairs) {
            if (mode) { i = p >> 4; j = p & 15; }
            else      { i = (int)((unsigned)p / (unsigned)nv); j = p - i * nv; }
        }
        const float* Ap = Arow + (size_t)i * 1024;
        const float* Bp = Brow + (size_t)j * 1024;
        int tbase = (w & 1) << 4;
#pragma unroll
        for (int cc = 0; cc < 16; ++cc) {
            int t = tbase + cc;
            int k0 = (t << 5) + (lh << 3);
            f32x4 a0 = *(const f32x4*)(Ap + k0), a1 = *(const f32x4*)(Ap + k0 + 4);
            f32x4 b0 = *(const f32x4*)(Bp + k0), b1 = *(const f32x4*)(Bp + k0 + 4);
            short8 v;
#pragma unroll
            for (int e = 0; e < 4; ++e) {
                v[e]     = f2bf(fmaxf(a0[e] + b0[e], 0.f));
                v[4 + e] = f2bf(fmaxf(a1[e] + b1[e], 0.f));
            }
            XL[swz((((mfp << 5) + t) << 6) + l)] = v;
        }
    }
    __syncthreads();

    // ---- GEMM1: Y = X @ W2  (wave cols w*128..+127)
    f32x4 z4 = {0.f, 0.f, 0.f, 0.f};
    f32x4 acc[4][8];
#pragma unroll
    for (int mf = 0; mf < 4; ++mf)
#pragma unroll
        for (int f = 0; f < 8; ++f) acc[mf][f] = z4;
    gemm_pipe(P.W2[mode] + ((size_t)w << 14) + l, XL, l, acc);
    __syncthreads();                                   // all X reads done

    // ---- epilogue 1: Y[m][k'] = relu(acc+b2), k' = w*128 + lr*8 + f.
    // One short8 (16B) write per (mf,r).
    {
        float b2l[8];
#pragma unroll
        for (int f = 0; f < 8; ++f) b2l[f] = P.b2[mode][(w << 7) + (f << 4) + lr];
#pragma unroll
        for (int mf = 0; mf < 4; ++mf)
#pragma unroll
            for (int r = 0; r < 4; ++r) {
                short8 v;
#pragma unroll
                for (int f = 0; f < 8; ++f)
                    v[f] = f2bf(fmaxf(acc[mf][f][r] + b2l[f], 0.f));
                int slot = (((mf << 5) + (w << 2) + (lr >> 2)) << 6)
                         + ((lr & 3) << 4) + (lh << 2) + r;
                XL[swz(slot)] = v;
            }
    }
    __syncthreads();

    // ---- GEMM2: Z = Y @ W3 (k'-space; W3 rows pre-permuted)
#pragma unroll
    for (int mf = 0; mf < 4; ++mf)
#pragma unroll
        for (int f = 0; f < 8; ++f) acc[mf][f] = z4;
    gemm_pipe(P.W3[mode] + ((size_t)w << 14) + l, XL, l, acc);

    // ---- masked row-sum of relu(acc+b3) -> one atomic per col
    float b3l[8];
#pragma unroll
    for (int f = 0; f < 8; ++f) b3l[f] = P.b3[mode][(w << 7) + (f << 4) + lr];
#pragma unroll
    for (int f = 0; f < 8; ++f) {
        float s = 0.f;
#pragma unroll
        for (int mf = 0; mf < 4; ++mf)
#pragma unroll
            for (int r = 0; r < 4; ++r) {
                int m = (mf << 4) + (lh << 2) + r;
                if (p0 + m < npairs) s += fmaxf(acc[mf][f][r] + b3l[f], 0.f);
            }
        s += __shfl_xor(s, 16);
        s += __shfl_xor(s, 32);
        if (l < 16) atomicAdd(&P.gsum[mode][(size_t)b * 1024 + (w << 7) + (f << 4) + l], s);
    }
}

// ---------------------------------------------------------------------------
// Tail (fp32, tiny)
// ---------------------------------------------------------------------------
__global__ __launch_bounds__(256) void k_t1(const float* g1s, const float* g2s,
                                            const float* f1_w, const float* f1_b,
                                            const float* f2_w, const float* f2_b,
                                            float* rn) {
    __shared__ float red[256];
    int bi = blockIdx.x;
    int s = bi >> 6, b = (bi >> 4) & 3, nb = bi & 15;
    int t = threadIdx.x, nl = t & 63, sl = t >> 6;
    int n = (nb << 6) + nl;
    const float* vin = (s ? g2s : g1s) + b * 1024;
    const float* W = s ? f2_w : f1_w;
    float p = 0.f;
    int k0 = sl << 8;
    for (int k = 0; k < 256; ++k) p += vin[k0 + k] * W[(size_t)(k0 + k) * 1024 + n];
    red[t] = p;
    __syncthreads();
    if (t < 64) {
        float tot = red[t] + red[t + 64] + red[t + 128] + red[t + 192];
        const float* bias = s ? f2_b : f1_b;
        int nn = (nb << 6) + t;
        rn[(size_t)b * 2048 + (s << 10) + nn] = fmaxf(tot + bias[nn], 0.f);
    }
}

__global__ __launch_bounds__(256) void k_t2(const float* rn, const float* fg_w1,
                                            const float* fg_b1, float* u) {
    __shared__ float red[256];
    int bi = blockIdx.x;
    int b = bi >> 4, nb = bi & 15;
    int t = threadIdx.x, nl = t & 63, sl = t >> 6;
    int n = (nb << 6) + nl;
    float p = 0.f;
    int k0 = sl << 9;
    for (int k = 0; k < 512; ++k) p += rn[(size_t)b * 2048 + k0 + k] * fg_w1[(size_t)(k0 + k) * 1024 + n];
    red[t] = p;
    __syncthreads();
    if (t < 64) {
        float tot = red[t] + red[t + 64] + red[t + 128] + red[t + 192];
        int nn = (nb << 6) + t;
        u[(size_t)b * 1024 + nn] = fmaxf(tot + fg_b1[nn], 0.f);
    }
}

__global__ __launch_bounds__(256) void k_t3(const float* u, const float* fg_w2,
                                            const float* fg_b2, float* out) {
    __shared__ float red[256];
    int b = blockIdx.x;
    int t = threadIdx.x, c = t & 15, sl = t >> 4;
    float p = 0.f;
    int k0 = sl << 6;
    for (int k = 0; k < 64; ++k) p += u[(size_t)b * 1024 + k0 + k] * fg_w2[(size_t)(k0 + k) * 16 + c];
    red[t] = p;
    __syncthreads();
    if (t < 16) {
        float tot = 0.f;
#pragma unroll
        for (int s2 = 0; s2 < 16; ++s2) tot += red[t + (s2 << 4)];
        out[b * 16 + t] = tot + fg_b2[t];
    }
}

// ---------------------------------------------------------------------------
extern "C" void kernel_launch(void* const* d_in, const int* in_sizes, int n_in,
                              void* d_out, int out_size, void* d_ws, size_t ws_size,
                              hipStream_t stream) {
    (void)in_sizes; (void)n_in; (void)out_size; (void)ws_size;
    const float* pooled      = (const float*)d_in[1];
    const float* box_feats   = (const float*)d_in[2];
    const float* q_feats     = (const float*)d_in[3];
    const float* box_coords  = (const float*)d_in[4];
    const int*   index       = (const int*)d_in[5];
    const float* g1_w1 = (const float*)d_in[6];
    const float* g1_b1 = (const float*)d_in[7];
    const float* g1_w2 = (const float*)d_in[8];
    const float* g1_b2 = (const float*)d_in[9];
    const float* g1_w3 = (const float*)d_in[10];
    const float* g1_b3 = (const float*)d_in[11];
    const float* f1_w  = (const float*)d_in[12];
    const float* f1_b  = (const float*)d_in[13];
    const float* g2_w1 = (const float*)d_in[14];
    const float* g2_b1 = (const float*)d_in[15];
    const float* g2_w2 = (const float*)d_in[16];
    const float* g2_b2 = (const float*)d_in[17];
    const float* g2_w3 = (const float*)d_in[18];
    const float* g2_b3 = (const float*)d_in[19];
    const float* f2_w  = (const float*)d_in[20];
    const float* f2_b  = (const float*)d_in[21];
    const float* fg_w1 = (const float*)d_in[22];
    const float* fg_b1 = (const float*)d_in[23];
    const float* fg_w2 = (const float*)d_in[24];
    const float* fg_b2 = (const float*)d_in[25];
    const float* pool_coords = (const float*)d_in[26];
    float* out = (float*)d_out;

    char* base = (char*)d_ws;
    size_t off = 0;
    auto alloc = [&](size_t bytes) -> void* {
        void* p = base + off;
        off = (off + bytes + 255) & ~(size_t)255;
        return p;
    };
    const size_t szWf98 = (size_t)98 * 64 * 64 * 16;  // 6.4 MB
    const size_t szWf65 = (size_t)65 * 64 * 64 * 16;  // 4.26 MB
    const size_t szWf32 = (size_t)32 * 64 * 64 * 16;  // 2 MB
    short* WfA   = (short*)alloc(szWf98);
    short* WfB   = (short*)alloc(szWf65);
    short* Wf2A  = (short*)alloc(szWf98);
    short* Wf2B  = (short*)alloc(szWf65);
    short* Wg1w2 = (short*)alloc(szWf32);
    short* Wg1w3 = (short*)alloc(szWf32);
    short* Wg2w2 = (short*)alloc(szWf32);
    short* Wg2w3 = (short*)alloc(szWf32);
    short* bfcq  = (short*)alloc((size_t)512 * 3136 * 2);
    short* pc    = (short*)alloc((size_t)64 * 2080 * 2);
    float* A1    = (float*)alloc((size_t)512 * 1024 * 4);
    float* B1    = (float*)alloc((size_t)512 * 1024 * 4);
    float* A2    = (float*)alloc((size_t)512 * 1024 * 4);
    float* P2    = (float*)alloc((size_t)64 * 1024 * 4);
    float* sums  = (float*)alloc((size_t)2 * 4096 * 4);
    float* g1s   = sums;
    float* g2s   = sums + 4096;
    float* rn    = (float*)alloc((size_t)4 * 2048 * 4);
    float* u     = (float*)alloc((size_t)4 * 1024 * 4);

    // 0. zero accumulators early (independent of other work)
    hipMemsetAsync(sums, 0, 2 * 4096 * 4, stream);

    // 1. repack weights (W3s get the 128-block pi^-1 k-permutation)
    WConvP wp;
    for (int y = 0; y < 8; ++y) { wp.srcq[y] = nullptr; wp.bias[y] = nullptr; wp.perm[y] = 0; }
    wp.src0[0] = g1_w1;                      wp.srcq[0] = g1_w1 + (size_t)4104*1024; wp.bias[0] = g1_b1;
    wp.dst[0] = WfA;   wp.n0[0] = 2052; wp.nK[0] = 98;
    wp.src0[1] = g1_w1 + (size_t)2052*1024;  wp.dst[1] = WfB;   wp.n0[1] = 2052; wp.nK[1] = 65;
    wp.src0[2] = g2_w1;                      wp.srcq[2] = g2_w1 + (size_t)4104*1024; wp.bias[2] = g2_b1;
    wp.dst[2] = Wf2A;  wp.n0[2] = 2052; wp.nK[2] = 98;
    wp.src0[3] = g2_w1 + (size_t)2052*1024;  wp.dst[3] = Wf2B;  wp.n0[3] = 2052; wp.nK[3] = 65;
    wp.src0[4] = g1_w2; wp.dst[4] = Wg1w2; wp.n0[4] = 1024; wp.nK[4] = 32;
    wp.src0[5] = g1_w3; wp.dst[5] = Wg1w3; wp.n0[5] = 1024; wp.nK[5] = 32; wp.perm[5] = 1;
    wp.src0[6] = g2_w2; wp.dst[6] = Wg2w2; wp.n0[6] = 1024; wp.nK[6] = 32;
    wp.src0[7] = g2_w3; wp.dst[7] = Wg2w3; wp.n0[7] = 1024; wp.nK[7] = 32; wp.perm[7] = 1;
    k_wconv<<<dim3(1568, 8), 256, 0, stream>>>(wp);

    // 2. padded bf16 activations (q + bias-row appended for A-paths)
    k_build<<<dim3(6272, 2), 256, 0, stream>>>(box_feats, box_coords, pooled, pool_coords,
                                               q_feats, bfcq, pc);

    // 3. stage-1 GEMMs: A1 (hq1+b1 folded), B1, A2 (hq2+b1 folded), P2
    S1P sp;
    sp.X[0] = bfcq; sp.Wf[0] = (const short8*)WfA;  sp.Out[0] = A1; sp.xstr[0] = 3136; sp.nK[0] = 98;
    sp.X[1] = bfcq; sp.Wf[1] = (const short8*)WfB;  sp.Out[1] = B1; sp.xstr[1] = 3136; sp.nK[1] = 65;
    sp.X[2] = bfcq; sp.Wf[2] = (const short8*)Wf2A; sp.Out[2] = A2; sp.xstr[2] = 3136; sp.nK[2] = 98;
    sp.X[3] = pc;   sp.Wf[3] = (const short8*)Wf2B; sp.Out[3] = P2; sp.xstr[3] = 2080; sp.nK[3] = 65;
    k_stage1<<<200, 256, 0, stream>>>(sp);

    // 4. fused g1 (blocks 0..255, pairs=n*n) + g2 (blocks 256..287, pairs=n*16)
    FuseP fp;
    fp.Arow[0] = A1; fp.Brow[0] = B1;
    fp.W2[0] = (const short8*)Wg1w2; fp.W3[0] = (const short8*)Wg1w3;
    fp.b2[0] = g1_b2; fp.b3[0] = g1_b3; fp.gsum[0] = g1s;
    fp.Arow[1] = A2; fp.Brow[1] = P2;
    fp.W2[1] = (const short8*)Wg2w2; fp.W3[1] = (const short8*)Wg2w3;
    fp.b2[1] = g2_b2; fp.b3[1] = g2_b3; fp.gsum[1] = g2s;
    fp.index = index;
    k_fused<<<dim3(288, 4), 512, 0, stream>>>(fp);

    // 5-7. tail
    k_t1<<<128, 256, 0, stream>>>(g1s, g2s, f1_w, f1_b, f2_w, f2_b, rn);
    k_t2<<<64, 256, 0, stream>>>(rn, fg_w1, fg_b1, u);
    k_t3<<<4, 256, 0, stream>>>(u, fg_w2, fg_b2, out);
}